// Round 1
// baseline (401.407 us; speedup 1.0000x reference)
//
#include <hip/hip_runtime.h>
#include <hip/hip_bf16.h>

#define DIM 2048
#define T_SEQ 2048
#define B_SZ 2
#define NH 16
#define NKV 4
#define HD 128
#define M_ROWS (B_SZ * T_SEQ)  // 4096
#define KVDIM (NKV * HD)       // 512

typedef float f32x4 __attribute__((ext_vector_type(4)));
typedef __bf16 bf16x8 __attribute__((ext_vector_type(8)));
typedef short s16x4 __attribute__((ext_vector_type(4)));
typedef unsigned short u16x8 __attribute__((ext_vector_type(8)));

static __device__ __forceinline__ float bf2f(unsigned short u) {
    unsigned v = ((unsigned)u) << 16;
    return __builtin_bit_cast(float, v);
}
static __device__ __forceinline__ unsigned short f2bf(float f) {
    unsigned u = __builtin_bit_cast(unsigned, f);
    unsigned r = (u + 0x7fffu + ((u >> 16) & 1u)) >> 16;
    return (unsigned short)r;
}

// ---------------- elementwise f32 -> bf16 ----------------
__global__ void cvt_f32_bf16(const float* __restrict__ src, unsigned short* __restrict__ dst, int n4) {
    int i = blockIdx.x * blockDim.x + threadIdx.x;
    if (i >= n4) return;
    float4 v = ((const float4*)src)[i];
    ushort4 o;
    o.x = f2bf(v.x); o.y = f2bf(v.y); o.z = f2bf(v.z); o.w = f2bf(v.w);
    ((ushort4*)dst)[i] = o;
}

// ---------------- transpose + convert: src[K][N] f32 -> dst[N][K] bf16 ----------------
__global__ void transpose_cvt(const float* __restrict__ src, unsigned short* __restrict__ dst, int K, int N) {
    __shared__ float tl[32][33];
    const int tx = threadIdx.x, ty = threadIdx.y;
    const int n0 = blockIdx.x * 32, k0 = blockIdx.y * 32;
#pragma unroll
    for (int i = 0; i < 4; ++i)
        tl[ty + i * 8][tx] = src[(size_t)(k0 + ty + i * 8) * N + n0 + tx];
    __syncthreads();
#pragma unroll
    for (int i = 0; i < 4; ++i)
        dst[(size_t)(n0 + ty + i * 8) * K + k0 + tx] = f2bf(tl[tx][ty + i * 8]);
}

// ---------------- GEMM: C[M][N] = A[M][K] * BT[N][K]^T  (bf16 in, fp32 acc) ----------------
static __device__ __forceinline__ void store_out(float* p, float v) { *p = v; }
static __device__ __forceinline__ void store_out(unsigned short* p, float v) { *p = f2bf(v); }

template <typename OutT>
__global__ __launch_bounds__(256) void gemm_bt(const unsigned short* __restrict__ A,
                                               const unsigned short* __restrict__ BT,
                                               OutT* __restrict__ C, int M, int N, int K) {
    __shared__ __align__(16) unsigned short Al[128][40];
    __shared__ __align__(16) unsigned short Bl[128][40];
    const int m0 = blockIdx.x * 128, n0 = blockIdx.y * 128;
    const int t = threadIdx.x;
    const int lane = t & 63, w = t >> 6;
    const int wr = w >> 1, wc = w & 1;
    const int grp = lane >> 4, c = lane & 15;
    f32x4 acc[4][4] = {};
    for (int k0 = 0; k0 < K; k0 += 32) {
#pragma unroll
        for (int rr = 0; rr < 2; ++rr) {
            int idx = rr * 256 + t;
            int row = idx >> 2, cq = idx & 3;
            u16x8 va = *(const u16x8*)(A + (size_t)(m0 + row) * K + k0 + cq * 8);
            *(u16x8*)&Al[row][cq * 8] = va;
            u16x8 vb = *(const u16x8*)(BT + (size_t)(n0 + row) * K + k0 + cq * 8);
            *(u16x8*)&Bl[row][cq * 8] = vb;
        }
        __syncthreads();
        bf16x8 af[4], bfr[4];
#pragma unroll
        for (int i = 0; i < 4; ++i) af[i] = *(const bf16x8*)&Al[wr * 64 + i * 16 + c][grp * 8];
#pragma unroll
        for (int j = 0; j < 4; ++j) bfr[j] = *(const bf16x8*)&Bl[wc * 64 + j * 16 + c][grp * 8];
#pragma unroll
        for (int i = 0; i < 4; ++i)
#pragma unroll
            for (int j = 0; j < 4; ++j)
                acc[i][j] = __builtin_amdgcn_mfma_f32_16x16x32_bf16(af[i], bfr[j], acc[i][j], 0, 0, 0);
        __syncthreads();
    }
#pragma unroll
    for (int i = 0; i < 4; ++i)
#pragma unroll
        for (int j = 0; j < 4; ++j)
#pragma unroll
            for (int r = 0; r < 4; ++r) {
                int row = m0 + wr * 64 + i * 16 + grp * 4 + r;
                int col = n0 + wc * 64 + j * 16 + c;
                store_out(&C[(size_t)row * N + col], acc[i][j][r]);
            }
}

// ---------------- RoPE + repack to [B,H,T,hd] ----------------
__global__ __launch_bounds__(256) void rope_pack(const unsigned short* __restrict__ qbf,
                                                 const unsigned short* __restrict__ kbf,
                                                 const unsigned short* __restrict__ vbf,
                                                 unsigned short* __restrict__ Qb,
                                                 unsigned short* __restrict__ Kb,
                                                 unsigned short* __restrict__ Vb) {
    const int bt = blockIdx.x;
    const int b = bt >> 11, tt = bt & 2047;
    __shared__ float cs[64], sn[64];
    const int tid = threadIdx.x;
    if (tid < 64) {
        float inv = __powf(10000.0f, -(float)tid * (1.0f / 64.0f));
        float ang = (float)tt * inv;
        cs[tid] = cosf(ang);
        sn[tid] = sinf(ang);
    }
    __syncthreads();
    const float scale = 0.08838834764831845f;  // 128^-0.5
    for (int idx = tid; idx < NH * 64; idx += 256) {
        const int h = idx >> 6, i = idx & 63;
        const size_t src = (size_t)bt * DIM + h * HD;
        float x1 = bf2f(qbf[src + i]), x2 = bf2f(qbf[src + i + 64]);
        const size_t dst = (((size_t)(b * NH + h)) * T_SEQ + tt) * HD;
        Qb[dst + i] = f2bf((x1 * cs[i] - x2 * sn[i]) * scale);
        Qb[dst + i + 64] = f2bf((x2 * cs[i] + x1 * sn[i]) * scale);
    }
    {
        const int g = tid >> 6, i = tid & 63;
        const size_t src = (size_t)bt * KVDIM + g * HD;
        float x1 = bf2f(kbf[src + i]), x2 = bf2f(kbf[src + i + 64]);
        const size_t dst = (((size_t)(b * NKV + g)) * T_SEQ + tt) * HD;
        Kb[dst + i] = f2bf(x1 * cs[i] - x2 * sn[i]);
        Kb[dst + i + 64] = f2bf(x2 * cs[i] + x1 * sn[i]);
    }
    for (int idx = tid; idx < 2 * 256; idx += 256) {
        const int g = idx >> 7, i = idx & 127;
        const size_t dst = (((size_t)(b * NKV + g)) * T_SEQ + tt) * HD;
        Vb[dst + i] = vbf[(size_t)bt * KVDIM + g * HD + i];
    }
}

// ---------------- causal GQA flash attention ----------------
// grid (B*NH, T/64), block 256. Wave w handles 16 q rows. kv tiles of 16.
// Swapped QK^T: sT = mfma(Kfrag, Qfrag) -> lane holds S[q = lane&15][kv = 4*(lane>>4)+r]
__global__ __launch_bounds__(256) void attn_kernel(const unsigned short* __restrict__ Qb,
                                                   const unsigned short* __restrict__ Kb,
                                                   const unsigned short* __restrict__ Vb,
                                                   unsigned short* __restrict__ Ob) {
    __shared__ __align__(16) unsigned short Kl[16][136];
    __shared__ __align__(16) unsigned short Vl[16][136];
    const int bh = blockIdx.x;
    const int b = bh >> 4, h = bh & 15;
    const int gkv = h >> 2;
    const int qtile = blockIdx.y;
    const int t = threadIdx.x, lane = t & 63, w = t >> 6;
    const int q0 = qtile * 64 + w * 16;
    const int grp = lane >> 4, c = lane & 15;

    const size_t qbase = (((size_t)(b * NH + h) * T_SEQ) + q0 + c) * HD;
    bf16x8 qf[4];
#pragma unroll
    for (int kk = 0; kk < 4; ++kk) qf[kk] = *(const bf16x8*)(Qb + qbase + kk * 32 + grp * 8);

    const size_t kvbase = ((size_t)(b * NKV + gkv) * T_SEQ) * HD;
    f32x4 o[8] = {};
    float m_run = -INFINITY, l_run = 0.0f;
    const int ntiles = qtile * 4 + 4;
    const int qrow = q0 + c;

    for (int kt = 0; kt < ntiles; ++kt) {
        {
            const int sr = t >> 4, scq = t & 15;
            u16x8 kvv = *(const u16x8*)(Kb + kvbase + (size_t)(kt * 16 + sr) * HD + scq * 8);
            *(u16x8*)&Kl[sr][scq * 8] = kvv;
            u16x8 vvv = *(const u16x8*)(Vb + kvbase + (size_t)(kt * 16 + sr) * HD + scq * 8);
            *(u16x8*)&Vl[sr][scq * 8] = vvv;
        }
        __syncthreads();
        if (kt * 16 <= q0 + 15) {
            f32x4 s = {};
#pragma unroll
            for (int kk = 0; kk < 4; ++kk) {
                bf16x8 kf = *(const bf16x8*)&Kl[c][kk * 32 + grp * 8];
                s = __builtin_amdgcn_mfma_f32_16x16x32_bf16(kf, qf[kk], s, 0, 0, 0);
            }
            float p[4];
            float tm = -INFINITY;
#pragma unroll
            for (int r = 0; r < 4; ++r) {
                int kvg = kt * 16 + grp * 4 + r;
                float sv = s[r];
                if (kvg > qrow) sv = -1e30f;
                p[r] = sv;
                tm = fmaxf(tm, sv);
            }
            tm = fmaxf(tm, __shfl_xor(tm, 16));
            tm = fmaxf(tm, __shfl_xor(tm, 32));
            float m_new = fmaxf(m_run, tm);
            float alpha = __expf(m_run - m_new);
            float ls = 0.f;
#pragma unroll
            for (int r = 0; r < 4; ++r) {
                p[r] = __expf(p[r] - m_new);
                ls += p[r];
            }
            ls += __shfl_xor(ls, 16);
            ls += __shfl_xor(ls, 32);
            l_run = l_run * alpha + ls;
            m_run = m_new;
            float ao[4];
#pragma unroll
            for (int r = 0; r < 4; ++r) ao[r] = __shfl(alpha, grp * 4 + r);
#pragma unroll
            for (int dt = 0; dt < 8; ++dt)
#pragma unroll
                for (int r = 0; r < 4; ++r) o[dt][r] *= ao[r];
            s16x4 pa;
#pragma unroll
            for (int r = 0; r < 4; ++r) pa[r] = (short)f2bf(p[r]);
#pragma unroll
            for (int dt = 0; dt < 8; ++dt) {
                s16x4 vf;
#pragma unroll
                for (int j = 0; j < 4; ++j) vf[j] = (short)Vl[grp * 4 + j][dt * 16 + c];
                o[dt] = __builtin_amdgcn_mfma_f32_16x16x16bf16_1k(pa, vf, o[dt], 0, 0, 0);
            }
        }
        __syncthreads();
    }
    float lo[4];
#pragma unroll
    for (int r = 0; r < 4; ++r) lo[r] = 1.0f / __shfl(l_run, grp * 4 + r);
#pragma unroll
    for (int dt = 0; dt < 8; ++dt)
#pragma unroll
        for (int r = 0; r < 4; ++r) {
            int trow = q0 + grp * 4 + r;
            int col = h * HD + dt * 16 + c;
            Ob[((size_t)(b * T_SEQ) + trow) * DIM + col] = f2bf(o[dt][r] * lo[r]);
        }
}

extern "C" void kernel_launch(void* const* d_in, const int* in_sizes, int n_in,
                              void* d_out, int out_size, void* d_ws, size_t ws_size,
                              hipStream_t stream) {
    const float* x = (const float*)d_in[0];
    const float* wq = (const float*)d_in[1];
    const float* wk = (const float*)d_in[2];
    const float* wv = (const float*)d_in[3];
    const float* wo = (const float*)d_in[4];
    float* out = (float*)d_out;

    char* ws = (char*)d_ws;
    size_t off = 0;
    auto alloc = [&](size_t bytes) {
        char* p = ws + off;
        off = (off + bytes + 255) & ~(size_t)255;
        return p;
    };
    unsigned short* xb  = (unsigned short*)alloc((size_t)M_ROWS * DIM * 2);
    unsigned short* wqT = (unsigned short*)alloc((size_t)DIM * DIM * 2);
    unsigned short* wkT = (unsigned short*)alloc((size_t)KVDIM * DIM * 2);
    unsigned short* wvT = (unsigned short*)alloc((size_t)KVDIM * DIM * 2);
    unsigned short* woT = (unsigned short*)alloc((size_t)DIM * DIM * 2);
    unsigned short* qbf = (unsigned short*)alloc((size_t)M_ROWS * DIM * 2);
    unsigned short* kbf = (unsigned short*)alloc((size_t)M_ROWS * KVDIM * 2);
    unsigned short* vbf = (unsigned short*)alloc((size_t)M_ROWS * KVDIM * 2);
    unsigned short* Qb  = (unsigned short*)alloc((size_t)M_ROWS * DIM * 2);
    unsigned short* Kb  = (unsigned short*)alloc((size_t)M_ROWS * KVDIM * 2);
    unsigned short* Vb  = (unsigned short*)alloc((size_t)M_ROWS * KVDIM * 2);
    unsigned short* attn = qbf;  // alias: qbf is dead after rope_pack

    cvt_f32_bf16<<<(M_ROWS * DIM / 4 + 255) / 256, 256, 0, stream>>>(x, xb, M_ROWS * DIM / 4);
    dim3 tb(32, 8);
    transpose_cvt<<<dim3(DIM / 32, DIM / 32), tb, 0, stream>>>(wq, wqT, DIM, DIM);
    transpose_cvt<<<dim3(KVDIM / 32, DIM / 32), tb, 0, stream>>>(wk, wkT, DIM, KVDIM);
    transpose_cvt<<<dim3(KVDIM / 32, DIM / 32), tb, 0, stream>>>(wv, wvT, DIM, KVDIM);
    transpose_cvt<<<dim3(DIM / 32, DIM / 32), tb, 0, stream>>>(wo, woT, DIM, DIM);

    gemm_bt<unsigned short><<<dim3(M_ROWS / 128, DIM / 128), 256, 0, stream>>>(xb, wqT, qbf, M_ROWS, DIM, DIM);
    gemm_bt<unsigned short><<<dim3(M_ROWS / 128, KVDIM / 128), 256, 0, stream>>>(xb, wkT, kbf, M_ROWS, KVDIM, DIM);
    gemm_bt<unsigned short><<<dim3(M_ROWS / 128, KVDIM / 128), 256, 0, stream>>>(xb, wvT, vbf, M_ROWS, KVDIM, DIM);

    rope_pack<<<M_ROWS, 256, 0, stream>>>(qbf, kbf, vbf, Qb, Kb, Vb);

    attn_kernel<<<dim3(B_SZ * NH, T_SEQ / 64), 256, 0, stream>>>(Qb, Kb, Vb, attn);

    gemm_bt<float><<<dim3(M_ROWS / 128, DIM / 128), 256, 0, stream>>>(attn, woT, out, M_ROWS, DIM, DIM);
}

// Round 2
// 258.710 us; speedup vs baseline: 1.5516x; 1.5516x over previous
//
#include <hip/hip_runtime.h>
#include <hip/hip_bf16.h>

#define DIM 2048
#define T_SEQ 2048
#define B_SZ 2
#define NH 16
#define NKV 4
#define HD 128
#define KVDIM (NKV * HD)            // 512
#define M_ROWS (B_SZ * T_SEQ)       // 4096
#define QKVN (DIM + 2 * KVDIM)      // 3072
#define QBLK 128
#define KVBLK 64

typedef float f32x4 __attribute__((ext_vector_type(4)));
typedef __bf16 bf16x8 __attribute__((ext_vector_type(8)));
typedef short s16x4 __attribute__((ext_vector_type(4)));
typedef unsigned short u16x8 __attribute__((ext_vector_type(8)));

static __device__ __forceinline__ float bf2f(unsigned short u) {
    unsigned v = ((unsigned)u) << 16;
    return __builtin_bit_cast(float, v);
}
static __device__ __forceinline__ unsigned short f2bf(float f) {
    unsigned u = __builtin_bit_cast(unsigned, f);
    unsigned r = (u + 0x7fffu + ((u >> 16) & 1u)) >> 16;
    return (unsigned short)r;
}

static __device__ __forceinline__ void gload16(const void* g, void* l) {
    __builtin_amdgcn_global_load_lds((const __attribute__((address_space(1))) void*)g,
                                     (__attribute__((address_space(3))) void*)l, 16, 0, 0);
}

// ---------------- elementwise f32 -> bf16 ----------------
__global__ void cvt_f32_bf16(const float* __restrict__ src, unsigned short* __restrict__ dst, int n4) {
    int i = blockIdx.x * blockDim.x + threadIdx.x;
    if (i >= n4) return;
    float4 v = ((const float4*)src)[i];
    ushort4 o;
    o.x = f2bf(v.x); o.y = f2bf(v.y); o.z = f2bf(v.z); o.w = f2bf(v.w);
    ((ushort4*)dst)[i] = o;
}

// ---------------- RoPE cos/sin table [T][64] ----------------
__global__ void build_tab(float2* __restrict__ tab) {
    const int idx = blockIdx.x * 256 + threadIdx.x;
    if (idx >= T_SEQ * 64) return;
    const int tt = idx >> 6, i = idx & 63;
    const float inv = exp2f(-(float)i * (13.287712379549449f / 64.0f));  // 10000^(-i/64)
    const float ang = (float)tt * inv;
    tab[idx] = make_float2(cosf(ang), sinf(ang));
}

// ---------------- transpose + convert: src[K][N] f32 -> dst[N][K] bf16 ----------------
__global__ void transpose_cvt(const float* __restrict__ src, unsigned short* __restrict__ dst, int K, int N) {
    __shared__ float tl[32][33];
    const int tx = threadIdx.x, ty = threadIdx.y;
    const int n0 = blockIdx.x * 32, k0 = blockIdx.y * 32;
#pragma unroll
    for (int i = 0; i < 4; ++i)
        tl[ty + i * 8][tx] = src[(size_t)(k0 + ty + i * 8) * N + n0 + tx];
    __syncthreads();
#pragma unroll
    for (int i = 0; i < 4; ++i)
        dst[(size_t)(n0 + ty + i * 8) * K + k0 + tx] = f2bf(tl[tx][ty + i * 8]);
}

// ---------------- transpose V: Vb[b,g][T][HD] -> Vt[b,g][HD][T] ----------------
__global__ void transpose_v(const unsigned short* __restrict__ Vb, unsigned short* __restrict__ Vt) {
    __shared__ unsigned short tl[32][33];
    const int t0 = blockIdx.x * 32;
    const int d0 = blockIdx.y * 32;
    const int bg = blockIdx.z;
    const unsigned short* src = Vb + (size_t)bg * T_SEQ * HD;
    unsigned short* dst = Vt + (size_t)bg * T_SEQ * HD;
    const int tx = threadIdx.x, ty = threadIdx.y;
#pragma unroll
    for (int i = 0; i < 4; ++i)
        tl[ty + i * 8][tx] = src[(size_t)(t0 + ty + i * 8) * HD + d0 + tx];
    __syncthreads();
#pragma unroll
    for (int i = 0; i < 4; ++i)
        dst[(size_t)(d0 + ty + i * 8) * T_SEQ + t0 + tx] = tl[tx][ty + i * 8];
}

// ---------------- GEMM (m97 structure): C[M][N] = A[M][K] * BT[N][K]^T ----------------
static __device__ __forceinline__ void store_out(float* p, float v) { *p = v; }
static __device__ __forceinline__ void store_out(unsigned short* p, float v) { *p = f2bf(v); }

template <typename OutT>
__global__ __launch_bounds__(256) void gemm_bt(const unsigned short* __restrict__ A,
                                               const unsigned short* __restrict__ BT,
                                               OutT* __restrict__ C, int M, int N, int K) {
    __shared__ __align__(16) unsigned short Al[128 * 32];
    __shared__ __align__(16) unsigned short Bl[128 * 32];
    const int m0 = blockIdx.x * 128, n0 = blockIdx.y * 128;
    const int t = threadIdx.x;
    const int lane = t & 63, w = t >> 6;
    const int wr = w >> 1, wc = w & 1;
    const int grp = lane >> 4, c = lane & 15;
    const int srow = t >> 2, spart = t & 3;  // 4 threads per 32-col row, 8 u16 each
    const unsigned short* Ap0 = A + (size_t)(m0 + srow) * K + spart * 8;
    const unsigned short* Ap1 = A + (size_t)(m0 + 64 + srow) * K + spart * 8;
    const unsigned short* Bp0 = BT + (size_t)(n0 + srow) * K + spart * 8;
    const unsigned short* Bp1 = BT + (size_t)(n0 + 64 + srow) * K + spart * 8;
    unsigned short* la0 = Al + t * 8;
    unsigned short* la1 = Al + 64 * 32 + t * 8;
    unsigned short* lb0 = Bl + t * 8;
    unsigned short* lb1 = Bl + 64 * 32 + t * 8;
    f32x4 acc[4][4] = {};
    for (int k0 = 0; k0 < K; k0 += 32) {
        gload16(Ap0 + k0, la0);
        gload16(Ap1 + k0, la1);
        gload16(Bp0 + k0, lb0);
        gload16(Bp1 + k0, lb1);
        __syncthreads();
        bf16x8 af[4], bfr[4];
#pragma unroll
        for (int i = 0; i < 4; ++i) af[i] = *(const bf16x8*)(Al + (wr * 64 + i * 16 + c) * 32 + grp * 8);
#pragma unroll
        for (int j = 0; j < 4; ++j) bfr[j] = *(const bf16x8*)(Bl + (wc * 64 + j * 16 + c) * 32 + grp * 8);
#pragma unroll
        for (int i = 0; i < 4; ++i)
#pragma unroll
            for (int j = 0; j < 4; ++j)
                acc[i][j] = __builtin_amdgcn_mfma_f32_16x16x32_bf16(af[i], bfr[j], acc[i][j], 0, 0, 0);
        __syncthreads();
    }
#pragma unroll
    for (int i = 0; i < 4; ++i)
#pragma unroll
        for (int j = 0; j < 4; ++j)
#pragma unroll
            for (int r = 0; r < 4; ++r) {
                int row = m0 + wr * 64 + i * 16 + grp * 4 + r;
                int col = n0 + wc * 64 + j * 16 + c;
                store_out(&C[(size_t)row * N + col], acc[i][j][r]);
            }
}

// ---------------- RoPE + repack ----------------
// qkv[bt][3072]: Q cols 0..2047, K 2048..2559, V 2560..3071
// Q gets scale * log2(e) folded in (attention softmax runs in exp2 domain).
__global__ __launch_bounds__(256) void rope_pack(const unsigned short* __restrict__ qkv,
                                                 const float2* __restrict__ tab,
                                                 unsigned short* __restrict__ Qb,
                                                 unsigned short* __restrict__ Kb,
                                                 unsigned short* __restrict__ Vb) {
    const int bt = blockIdx.x;
    const int b = bt >> 11, tt = bt & 2047;
    __shared__ float cs[64], sn[64];
    const int tid = threadIdx.x;
    if (tid < 64) {
        float2 v = tab[tt * 64 + tid];
        cs[tid] = v.x;
        sn[tid] = v.y;
    }
    __syncthreads();
    const float qscale = 0.08838834764831845f * 1.4426950408889634f;
    const size_t src0 = (size_t)bt * QKVN;
#pragma unroll
    for (int iter = 0; iter < 4; ++iter) {
        const int idx = iter * 256 + tid;
        const int h = idx >> 6, i = idx & 63;
        const size_t src = src0 + h * HD;
        const float x1 = bf2f(qkv[src + i]), x2 = bf2f(qkv[src + i + 64]);
        const size_t dst = (((size_t)(b * NH + h)) * T_SEQ + tt) * HD;
        Qb[dst + i] = f2bf((x1 * cs[i] - x2 * sn[i]) * qscale);
        Qb[dst + i + 64] = f2bf((x2 * cs[i] + x1 * sn[i]) * qscale);
    }
    {
        const int gg = tid >> 6, i = tid & 63;
        const size_t src = src0 + DIM + gg * HD;
        const float x1 = bf2f(qkv[src + i]), x2 = bf2f(qkv[src + i + 64]);
        const size_t dst = (((size_t)(b * NKV + gg)) * T_SEQ + tt) * HD;
        Kb[dst + i] = f2bf(x1 * cs[i] - x2 * sn[i]);
        Kb[dst + i + 64] = f2bf(x2 * cs[i] + x1 * sn[i]);
    }
#pragma unroll
    for (int iter = 0; iter < 2; ++iter) {
        const int idx = iter * 256 + tid;
        const int gg = idx >> 7, i = idx & 127;
        const size_t dst = (((size_t)(b * NKV + gg)) * T_SEQ + tt) * HD;
        Vb[dst + i] = qkv[src0 + DIM + KVDIM + gg * HD + i];
    }
}

// ---------------- causal GQA flash attention ----------------
// 512 blocks (bh = bid&31, qt descending so heavy blocks first), 4 waves.
// Each wave: 32 q rows (2 x 16-row MFMA groups). KVBLK=64 staged per tile:
//   K in LDS with XOR swizzle (row&7)<<4; V transposed [d][kv] padded to 72.
// Swapped QK^T: s = mfma(K,Q) -> lane holds S[kv=grp*4+r][q=c]; PV uses
// 16x16x16 so P fragment needs no cross-lane movement.
__global__ __launch_bounds__(256) void attn_kernel(const unsigned short* __restrict__ Qb,
                                                   const unsigned short* __restrict__ Kb,
                                                   const unsigned short* __restrict__ Vt,
                                                   unsigned short* __restrict__ Ob) {
    __shared__ __align__(16) unsigned short Kl[KVBLK * HD];  // 64x128, swizzled
    __shared__ __align__(16) unsigned short Vl[HD][72];      // [d][kv], pad 64->72
    const int bid = blockIdx.x;
    const int bh = bid & 31;
    const int qt = (T_SEQ / QBLK - 1) - (bid >> 5);
    const int b = bh >> 4, h = bh & 15;
    const int g = h >> 2;
    const int t = threadIdx.x, lane = t & 63, w = t >> 6;
    const int grp = lane >> 4, c = lane & 15;
    const int q0 = qt * QBLK;
    const int wq = q0 + w * 32;

    bf16x8 qf[2][4];
#pragma unroll
    for (int qi = 0; qi < 2; ++qi) {
        const size_t qbase = ((size_t)(b * NH + h) * T_SEQ + wq + qi * 16 + c) * HD;
#pragma unroll
        for (int kk = 0; kk < 4; ++kk)
            qf[qi][kk] = *(const bf16x8*)(Qb + qbase + kk * 32 + grp * 8);
    }
    const size_t kbase = (size_t)(b * NKV + g) * T_SEQ * HD;
    const size_t vbase = (size_t)(b * NKV + g) * (size_t)HD * T_SEQ;

    f32x4 o[2][8] = {};
    float m_run[2] = {-1e30f, -1e30f};
    float l_run[2] = {0.f, 0.f};

    const int nkv = (q0 + QBLK) / KVBLK;
    for (int kt = 0; kt < nkv; ++kt) {
        const int kv0 = kt * KVBLK;
        // ---- stage K (swizzled) ----
#pragma unroll
        for (int i = 0; i < 4; ++i) {
            const int idx = i * 256 + t;
            const int row = idx >> 4, ch = idx & 15;
            u16x8 kvv = *(const u16x8*)(Kb + kbase + (size_t)(kv0 + row) * HD + ch * 8);
            *(u16x8*)((char*)Kl + row * 256 + ((ch * 16) ^ ((row & 7) << 4))) = kvv;
        }
        // ---- stage V transposed ----
#pragma unroll
        for (int i = 0; i < 4; ++i) {
            const int idx = i * 256 + t;
            const int dr = idx >> 3, ch = idx & 7;
            u16x8 vv = *(const u16x8*)(Vt + vbase + (size_t)dr * T_SEQ + kv0 + ch * 8);
            *(u16x8*)&Vl[dr][ch * 8] = vv;
        }
        __syncthreads();
        if (kv0 <= wq + 31) {
            f32x4 s[2][4] = {};
#pragma unroll
            for (int kvc = 0; kvc < 4; ++kvc) {
                const int row = kvc * 16 + c;
                bf16x8 kf[4];
#pragma unroll
                for (int kk = 0; kk < 4; ++kk)
                    kf[kk] = *(const bf16x8*)((const char*)Kl + row * 256 +
                                              ((kk * 64 + grp * 16) ^ ((row & 7) << 4)));
#pragma unroll
                for (int qi = 0; qi < 2; ++qi)
#pragma unroll
                    for (int kk = 0; kk < 4; ++kk)
                        s[qi][kvc] = __builtin_amdgcn_mfma_f32_16x16x32_bf16(kf[kk], qf[qi][kk], s[qi][kvc], 0, 0, 0);
            }
            s16x4 pa[2][4];
#pragma unroll
            for (int qi = 0; qi < 2; ++qi) {
                const int qmin = wq + qi * 16;
                if (kv0 + KVBLK - 1 > qmin) {  // diagonal tile: apply causal mask
#pragma unroll
                    for (int kvc = 0; kvc < 4; ++kvc)
#pragma unroll
                        for (int r = 0; r < 4; ++r) {
                            const int kvg = kv0 + kvc * 16 + grp * 4 + r;
                            if (kvg > qmin + c) s[qi][kvc][r] = -1e30f;
                        }
                }
                float tm = -1e30f;
#pragma unroll
                for (int kvc = 0; kvc < 4; ++kvc)
#pragma unroll
                    for (int r = 0; r < 4; ++r) tm = fmaxf(tm, s[qi][kvc][r]);
                tm = fmaxf(tm, __shfl_xor(tm, 16));
                tm = fmaxf(tm, __shfl_xor(tm, 32));
                const float m_new = fmaxf(m_run[qi], tm);
                const float alpha = exp2f(m_run[qi] - m_new);
                m_run[qi] = m_new;
                float p[16];
                float ls = 0.f;
#pragma unroll
                for (int kvc = 0; kvc < 4; ++kvc)
#pragma unroll
                    for (int r = 0; r < 4; ++r) {
                        const float pv = exp2f(s[qi][kvc][r] - m_new);
                        p[kvc * 4 + r] = pv;
                        ls += pv;
                    }
                ls += __shfl_xor(ls, 16);
                ls += __shfl_xor(ls, 32);
                l_run[qi] = l_run[qi] * alpha + ls;
                float ao[4];
#pragma unroll
                for (int r = 0; r < 4; ++r) ao[r] = __shfl(alpha, grp * 4 + r);
#pragma unroll
                for (int dt = 0; dt < 8; ++dt)
#pragma unroll
                    for (int r = 0; r < 4; ++r) o[qi][dt][r] *= ao[r];
#pragma unroll
                for (int kvc = 0; kvc < 4; ++kvc)
#pragma unroll
                    for (int r = 0; r < 4; ++r) pa[qi][kvc][r] = (short)f2bf(p[kvc * 4 + r]);
            }
            // ---- PV: V fragments shared across both q-groups ----
#pragma unroll
            for (int kvc = 0; kvc < 4; ++kvc)
#pragma unroll
                for (int dt = 0; dt < 8; ++dt) {
                    const s16x4 vf = *(const s16x4*)&Vl[dt * 16 + c][kvc * 16 + grp * 4];
                    o[0][dt] = __builtin_amdgcn_mfma_f32_16x16x16bf16_1k(pa[0][kvc], vf, o[0][dt], 0, 0, 0);
                    o[1][dt] = __builtin_amdgcn_mfma_f32_16x16x16bf16_1k(pa[1][kvc], vf, o[1][dt], 0, 0, 0);
                }
        }
        __syncthreads();
    }
#pragma unroll
    for (int qi = 0; qi < 2; ++qi) {
        float lo[4];
#pragma unroll
        for (int r = 0; r < 4; ++r) lo[r] = 1.0f / __shfl(l_run[qi], grp * 4 + r);
#pragma unroll
        for (int dt = 0; dt < 8; ++dt)
#pragma unroll
            for (int r = 0; r < 4; ++r) {
                const int trow = wq + qi * 16 + grp * 4 + r;
                Ob[((size_t)(b * T_SEQ) + trow) * DIM + h * HD + dt * 16 + c] = f2bf(o[qi][dt][r] * lo[r]);
            }
    }
}

extern "C" void kernel_launch(void* const* d_in, const int* in_sizes, int n_in,
                              void* d_out, int out_size, void* d_ws, size_t ws_size,
                              hipStream_t stream) {
    const float* x = (const float*)d_in[0];
    const float* wq = (const float*)d_in[1];
    const float* wk = (const float*)d_in[2];
    const float* wv = (const float*)d_in[3];
    const float* wo = (const float*)d_in[4];
    float* out = (float*)d_out;

    char* ws = (char*)d_ws;
    size_t off = 0;
    auto alloc = [&](size_t bytes) {
        char* p = ws + off;
        off = (off + bytes + 255) & ~(size_t)255;
        return p;
    };
    unsigned short* xb    = (unsigned short*)alloc((size_t)M_ROWS * DIM * 2);   // later: Qb
    unsigned short* wqkvT = (unsigned short*)alloc((size_t)QKVN * DIM * 2);     // later: Vt
    unsigned short* woT   = (unsigned short*)alloc((size_t)DIM * DIM * 2);
    unsigned short* qkv   = (unsigned short*)alloc((size_t)M_ROWS * QKVN * 2);  // later: attnO
    unsigned short* Kb    = (unsigned short*)alloc((size_t)M_ROWS * KVDIM * 2);
    unsigned short* Vb    = (unsigned short*)alloc((size_t)M_ROWS * KVDIM * 2);
    float2*         tab   = (float2*)alloc((size_t)T_SEQ * 64 * sizeof(float2));
    unsigned short* Qb    = xb;     // xb dead after QKV GEMM
    unsigned short* Vt    = wqkvT;  // wqkvT dead after QKV GEMM
    unsigned short* attnO = qkv;    // qkv dead after rope_pack

    cvt_f32_bf16<<<(M_ROWS * DIM / 4 + 255) / 256, 256, 0, stream>>>(x, xb, M_ROWS * DIM / 4);
    build_tab<<<(T_SEQ * 64 + 255) / 256, 256, 0, stream>>>(tab);

    dim3 tb(32, 8);
    transpose_cvt<<<dim3(DIM / 32, DIM / 32), tb, 0, stream>>>(wq, wqkvT, DIM, DIM);
    transpose_cvt<<<dim3(KVDIM / 32, DIM / 32), tb, 0, stream>>>(wk, wqkvT + (size_t)DIM * DIM, DIM, KVDIM);
    transpose_cvt<<<dim3(KVDIM / 32, DIM / 32), tb, 0, stream>>>(wv, wqkvT + (size_t)(DIM + KVDIM) * DIM, DIM, KVDIM);
    transpose_cvt<<<dim3(DIM / 32, DIM / 32), tb, 0, stream>>>(wo, woT, DIM, DIM);

    gemm_bt<unsigned short><<<dim3(M_ROWS / 128, QKVN / 128), 256, 0, stream>>>(xb, wqkvT, qkv, M_ROWS, QKVN, DIM);

    rope_pack<<<M_ROWS, 256, 0, stream>>>(qkv, tab, Qb, Kb, Vb);
    transpose_v<<<dim3(T_SEQ / 32, HD / 32, B_SZ * NKV), tb, 0, stream>>>(Vb, Vt);

    attn_kernel<<<(B_SZ * NH) * (T_SEQ / QBLK), 256, 0, stream>>>(Qb, Kb, Vt, attnO);

    gemm_bt<float><<<dim3(M_ROWS / 128, DIM / 128), 256, 0, stream>>>(attnO, woT, out, M_ROWS, DIM, DIM);
}

// Round 3
// 249.313 us; speedup vs baseline: 1.6101x; 1.0377x over previous
//
#include <hip/hip_runtime.h>
#include <hip/hip_bf16.h>

#define DIM 2048
#define T_SEQ 2048
#define B_SZ 2
#define NH 16
#define NKV 4
#define HD 128
#define KVDIM (NKV * HD)            // 512
#define M_ROWS (B_SZ * T_SEQ)       // 4096
#define QKVN (DIM + 2 * KVDIM)      // 3072
#define QBLK 128
#define KVBLK 64

typedef float f32x4 __attribute__((ext_vector_type(4)));
typedef __bf16 bf16x8 __attribute__((ext_vector_type(8)));
typedef unsigned short u16x8 __attribute__((ext_vector_type(8)));

static __device__ __forceinline__ float bf2f(unsigned short u) {
    unsigned v = ((unsigned)u) << 16;
    return __builtin_bit_cast(float, v);
}
static __device__ __forceinline__ unsigned short f2bf(float f) {
    unsigned u = __builtin_bit_cast(unsigned, f);
    unsigned r = (u + 0x7fffu + ((u >> 16) & 1u)) >> 16;
    return (unsigned short)r;
}

static __device__ __forceinline__ void gload16(const void* g, void* l) {
    __builtin_amdgcn_global_load_lds((const __attribute__((address_space(1))) void*)g,
                                     (__attribute__((address_space(3))) void*)l, 16, 0, 0);
}

// ---------------- elementwise f32 -> bf16 ----------------
__global__ void cvt_f32_bf16(const float* __restrict__ src, unsigned short* __restrict__ dst, int n4) {
    int i = blockIdx.x * blockDim.x + threadIdx.x;
    if (i >= n4) return;
    float4 v = ((const float4*)src)[i];
    ushort4 o;
    o.x = f2bf(v.x); o.y = f2bf(v.y); o.z = f2bf(v.z); o.w = f2bf(v.w);
    ((ushort4*)dst)[i] = o;
}

// ---------------- RoPE cos/sin table [T][64] ----------------
__global__ void build_tab(float2* __restrict__ tab) {
    const int idx = blockIdx.x * 256 + threadIdx.x;
    if (idx >= T_SEQ * 64) return;
    const int tt = idx >> 6, i = idx & 63;
    const float inv = exp2f(-(float)i * (13.287712379549449f / 64.0f));  // 10000^(-i/64)
    const float ang = (float)tt * inv;
    tab[idx] = make_float2(cosf(ang), sinf(ang));
}

// ---------------- transpose + convert: src[K][N] f32 -> dst[N][K] bf16 ----------------
__global__ void transpose_cvt(const float* __restrict__ src, unsigned short* __restrict__ dst, int K, int N) {
    __shared__ float tl[32][33];
    const int tx = threadIdx.x, ty = threadIdx.y;
    const int n0 = blockIdx.x * 32, k0 = blockIdx.y * 32;
#pragma unroll
    for (int i = 0; i < 4; ++i)
        tl[ty + i * 8][tx] = src[(size_t)(k0 + ty + i * 8) * N + n0 + tx];
    __syncthreads();
#pragma unroll
    for (int i = 0; i < 4; ++i)
        dst[(size_t)(n0 + ty + i * 8) * K + k0 + tx] = f2bf(tl[tx][ty + i * 8]);
}

// ---------------- transpose V: Vb[b,g][T][HD] -> Vt[b,g][HD][T] ----------------
__global__ void transpose_v(const unsigned short* __restrict__ Vb, unsigned short* __restrict__ Vt) {
    __shared__ unsigned short tl[32][33];
    const int t0 = blockIdx.x * 32;
    const int d0 = blockIdx.y * 32;
    const int bg = blockIdx.z;
    const unsigned short* src = Vb + (size_t)bg * T_SEQ * HD;
    unsigned short* dst = Vt + (size_t)bg * T_SEQ * HD;
    const int tx = threadIdx.x, ty = threadIdx.y;
#pragma unroll
    for (int i = 0; i < 4; ++i)
        tl[ty + i * 8][tx] = src[(size_t)(t0 + ty + i * 8) * HD + d0 + tx];
    __syncthreads();
#pragma unroll
    for (int i = 0; i < 4; ++i)
        dst[(size_t)(d0 + ty + i * 8) * T_SEQ + t0 + tx] = tl[tx][ty + i * 8];
}

// ---------------- GEMM (m97 structure + XCD swizzle): C[M][N] = A[M][K] * BT[N][K]^T ----------------
static __device__ __forceinline__ void store_out(float* p, float v) { *p = v; }
static __device__ __forceinline__ void store_out(unsigned short* p, float v) { *p = f2bf(v); }

template <typename OutT>
__global__ __launch_bounds__(256) void gemm_bt(const unsigned short* __restrict__ A,
                                               const unsigned short* __restrict__ BT,
                                               OutT* __restrict__ C, int M, int N, int K, int Mtiles) {
    __shared__ __align__(16) unsigned short Al[128 * 32];
    __shared__ __align__(16) unsigned short Bl[128 * 32];
    const int nwg = gridDim.x;
    const int cpx = nwg >> 3;                         // nwg % 8 == 0
    const int f = blockIdx.x;
    const int swz = (f & 7) * cpx + (f >> 3);
    const int m0 = (swz % Mtiles) * 128, n0 = (swz / Mtiles) * 128;
    const int t = threadIdx.x;
    const int lane = t & 63, w = t >> 6;
    const int wr = w >> 1, wc = w & 1;
    const int grp = lane >> 4, c = lane & 15;
    const int srow = t >> 2, spart = t & 3;  // 4 threads per 32-col row, 8 u16 each
    const unsigned short* Ap0 = A + (size_t)(m0 + srow) * K + spart * 8;
    const unsigned short* Ap1 = A + (size_t)(m0 + 64 + srow) * K + spart * 8;
    const unsigned short* Bp0 = BT + (size_t)(n0 + srow) * K + spart * 8;
    const unsigned short* Bp1 = BT + (size_t)(n0 + 64 + srow) * K + spart * 8;
    unsigned short* la0 = Al + t * 8;
    unsigned short* la1 = Al + 64 * 32 + t * 8;
    unsigned short* lb0 = Bl + t * 8;
    unsigned short* lb1 = Bl + 64 * 32 + t * 8;
    f32x4 acc[4][4] = {};
    for (int k0 = 0; k0 < K; k0 += 32) {
        gload16(Ap0 + k0, la0);
        gload16(Ap1 + k0, la1);
        gload16(Bp0 + k0, lb0);
        gload16(Bp1 + k0, lb1);
        __syncthreads();
        bf16x8 af[4], bfr[4];
#pragma unroll
        for (int i = 0; i < 4; ++i) af[i] = *(const bf16x8*)(Al + (wr * 64 + i * 16 + c) * 32 + grp * 8);
#pragma unroll
        for (int j = 0; j < 4; ++j) bfr[j] = *(const bf16x8*)(Bl + (wc * 64 + j * 16 + c) * 32 + grp * 8);
#pragma unroll
        for (int i = 0; i < 4; ++i)
#pragma unroll
            for (int j = 0; j < 4; ++j)
                acc[i][j] = __builtin_amdgcn_mfma_f32_16x16x32_bf16(af[i], bfr[j], acc[i][j], 0, 0, 0);
        __syncthreads();
    }
#pragma unroll
    for (int i = 0; i < 4; ++i)
#pragma unroll
        for (int j = 0; j < 4; ++j)
#pragma unroll
            for (int r = 0; r < 4; ++r) {
                int row = m0 + wr * 64 + i * 16 + grp * 4 + r;
                int col = n0 + wc * 64 + j * 16 + c;
                store_out(&C[(size_t)row * N + col], acc[i][j][r]);
            }
}

// ---------------- RoPE + repack ----------------
__global__ __launch_bounds__(256) void rope_pack(const unsigned short* __restrict__ qkv,
                                                 const float2* __restrict__ tab,
                                                 unsigned short* __restrict__ Qb,
                                                 unsigned short* __restrict__ Kb,
                                                 unsigned short* __restrict__ Vb) {
    const int bt = blockIdx.x;
    const int b = bt >> 11, tt = bt & 2047;
    __shared__ float cs[64], sn[64];
    const int tid = threadIdx.x;
    if (tid < 64) {
        float2 v = tab[tt * 64 + tid];
        cs[tid] = v.x;
        sn[tid] = v.y;
    }
    __syncthreads();
    const float qscale = 0.08838834764831845f * 1.4426950408889634f;  // 128^-0.5 * log2(e)
    const size_t src0 = (size_t)bt * QKVN;
#pragma unroll
    for (int iter = 0; iter < 4; ++iter) {
        const int idx = iter * 256 + tid;
        const int h = idx >> 6, i = idx & 63;
        const size_t src = src0 + h * HD;
        const float x1 = bf2f(qkv[src + i]), x2 = bf2f(qkv[src + i + 64]);
        const size_t dst = (((size_t)(b * NH + h)) * T_SEQ + tt) * HD;
        Qb[dst + i] = f2bf((x1 * cs[i] - x2 * sn[i]) * qscale);
        Qb[dst + i + 64] = f2bf((x2 * cs[i] + x1 * sn[i]) * qscale);
    }
    {
        const int gg = tid >> 6, i = tid & 63;
        const size_t src = src0 + DIM + gg * HD;
        const float x1 = bf2f(qkv[src + i]), x2 = bf2f(qkv[src + i + 64]);
        const size_t dst = (((size_t)(b * NKV + gg)) * T_SEQ + tt) * HD;
        Kb[dst + i] = f2bf(x1 * cs[i] - x2 * sn[i]);
        Kb[dst + i + 64] = f2bf(x2 * cs[i] + x1 * sn[i]);
    }
#pragma unroll
    for (int iter = 0; iter < 2; ++iter) {
        const int idx = iter * 256 + tid;
        const int gg = idx >> 7, i = idx & 127;
        const size_t dst = (((size_t)(b * NKV + gg)) * T_SEQ + tt) * HD;
        Vb[dst + i] = qkv[src0 + DIM + KVDIM + gg * HD + i];
    }
}

// ---------------- causal GQA flash attention ----------------
// 512 blocks heavy-first, 4 waves x 32 q-rows. KVBLK=64.
// K staged into LDS with PERMUTED row order: LDS slot (32ch + 16b + 4g + r) holds
// kv = 32ch + 8g + 4b + r. Then swapped QK^T (mfma(K,Q), S^T layout) leaves each
// lane holding P[q][kv=8*grp .. 8*grp+7] per 32-chunk == exactly the A-fragment of
// mfma_f32_16x16x32_bf16 for PV. Zero cross-lane repack; PV MFMA count halved.
// V pre-transposed [d][T]; LDS [d][72] (16B-aligned rows). Defer-max (THR=10,
// exp2 domain) skips O-rescale most tiles. T14: next tile global->reg loads issued
// before compute; reg->LDS write after barrier.
__global__ __launch_bounds__(256) void attn_kernel(const unsigned short* __restrict__ Qb,
                                                   const unsigned short* __restrict__ Kb,
                                                   const unsigned short* __restrict__ Vt,
                                                   unsigned short* __restrict__ Ob) {
    __shared__ __align__(16) unsigned short Kl[KVBLK * HD];  // 16KB, swizzled+permuted
    __shared__ __align__(16) unsigned short Vl[HD * 72];     // 18KB, [d][72]
    const int bid = blockIdx.x;
    const int bh = bid & 31;
    const int qt = (T_SEQ / QBLK - 1) - (bid >> 5);
    const int b = bh >> 4, h = bh & 15;
    const int g = h >> 2;
    const int t = threadIdx.x, lane = t & 63, w = t >> 6;
    const int grp = lane >> 4, c = lane & 15;
    const int q0 = qt * QBLK;
    const int wq = q0 + w * 32;

    bf16x8 qf[2][4];
#pragma unroll
    for (int qi = 0; qi < 2; ++qi) {
        const size_t qbase = ((size_t)(b * NH + h) * T_SEQ + wq + qi * 16 + c) * HD;
#pragma unroll
        for (int kk = 0; kk < 4; ++kk)
            qf[qi][kk] = *(const bf16x8*)(Qb + qbase + kk * 32 + grp * 8);
    }
    const size_t kbase = (size_t)(b * NKV + g) * T_SEQ * HD;
    const size_t vbase = (size_t)(b * NKV + g) * (size_t)HD * T_SEQ;

    // staging address tables
    const unsigned short* kp[4];
    const unsigned short* vp[4];
    int kd[4], vd[4];
#pragma unroll
    for (int i = 0; i < 4; ++i) {
        const int idx = i * 256 + t;
        const int rl = idx >> 4, ch = idx & 15;
        const int rl32 = rl & 31;
        const int kvrow = (rl >> 5) * 32 + ((rl32 >> 2) & 3) * 8 + (rl32 >> 4) * 4 + (rl32 & 3);
        kp[i] = Kb + kbase + (size_t)kvrow * HD + ch * 8;
        kd[i] = rl * 256 + ((ch * 16) ^ ((rl & 7) << 4));  // byte offset
        const int dr = idx >> 3, c8 = idx & 7;
        vp[i] = Vt + vbase + (size_t)dr * T_SEQ + c8 * 8;
        vd[i] = dr * 72 + c8 * 8;  // u16 offset
    }

    f32x4 o[2][8] = {};
    float m_run[2] = {-1e30f, -1e30f};
    float l_run[2] = {0.f, 0.f};

    const int nkv = (q0 + QBLK) / KVBLK;
    u16x8 kreg[4], vreg[4];
#pragma unroll
    for (int i = 0; i < 4; ++i) {
        kreg[i] = *(const u16x8*)kp[i];
        vreg[i] = *(const u16x8*)vp[i];
    }

    for (int kt = 0; kt < nkv; ++kt) {
        const int kv0 = kt * KVBLK;
        __syncthreads();
#pragma unroll
        for (int i = 0; i < 4; ++i) {
            *(u16x8*)((char*)Kl + kd[i]) = kreg[i];
            *(u16x8*)(Vl + vd[i]) = vreg[i];
        }
        __syncthreads();
        if (kt + 1 < nkv) {
#pragma unroll
            for (int i = 0; i < 4; ++i) {
                kreg[i] = *(const u16x8*)(kp[i] + (size_t)(kt + 1) * KVBLK * HD);
                vreg[i] = *(const u16x8*)(vp[i] + (kt + 1) * KVBLK);
            }
        }
        if (kv0 > wq + 31) continue;
        // ---- QK^T ----
        f32x4 s[2][4] = {};
#pragma unroll
        for (int kvc = 0; kvc < 4; ++kvc) {
            const int row = kvc * 16 + c;
            bf16x8 kf[4];
#pragma unroll
            for (int kk = 0; kk < 4; ++kk)
                kf[kk] = *(const bf16x8*)((const char*)Kl + row * 256 +
                                          ((kk * 64 + grp * 16) ^ ((row & 7) << 4)));
#pragma unroll
            for (int kk = 0; kk < 4; ++kk) {
                s[0][kvc] = __builtin_amdgcn_mfma_f32_16x16x32_bf16(kf[kk], qf[0][kk], s[0][kvc], 0, 0, 0);
                s[1][kvc] = __builtin_amdgcn_mfma_f32_16x16x32_bf16(kf[kk], qf[1][kk], s[1][kvc], 0, 0, 0);
            }
        }
        // ---- softmax (exp2 domain, defer-max) ----
        u16x8 pa[2][2];
#pragma unroll
        for (int qi = 0; qi < 2; ++qi) {
            const int qmin = wq + qi * 16;
            if (kv0 + KVBLK - 1 > qmin) {  // diagonal tile: causal mask (permuted kv decode)
#pragma unroll
                for (int kvc = 0; kvc < 4; ++kvc)
#pragma unroll
                    for (int r = 0; r < 4; ++r) {
                        const int kvg = kv0 + (kvc >> 1) * 32 + grp * 8 + (kvc & 1) * 4 + r;
                        if (kvg > qmin + c) s[qi][kvc][r] = -1e30f;
                    }
            }
            float tm = -1e30f;
#pragma unroll
            for (int kvc = 0; kvc < 4; ++kvc)
#pragma unroll
                for (int r = 0; r < 4; ++r) tm = fmaxf(tm, s[qi][kvc][r]);
            tm = fmaxf(tm, __shfl_xor(tm, 16));
            tm = fmaxf(tm, __shfl_xor(tm, 32));
            if (__any(tm > m_run[qi] + 10.0f)) {
                const float m_new = fmaxf(m_run[qi], tm);
                const float alpha = exp2f(m_run[qi] - m_new);
                m_run[qi] = m_new;
                l_run[qi] *= alpha;
                float ao[4];
#pragma unroll
                for (int r = 0; r < 4; ++r) ao[r] = __shfl(alpha, grp * 4 + r);
#pragma unroll
                for (int dt = 0; dt < 8; ++dt)
#pragma unroll
                    for (int r = 0; r < 4; ++r) o[qi][dt][r] *= ao[r];
            }
            float p[16];
            float ls = 0.f;
#pragma unroll
            for (int kvc = 0; kvc < 4; ++kvc)
#pragma unroll
                for (int r = 0; r < 4; ++r) {
                    const float pv = exp2f(s[qi][kvc][r] - m_run[qi]);
                    p[kvc * 4 + r] = pv;
                    ls += pv;
                }
            ls += __shfl_xor(ls, 16);
            ls += __shfl_xor(ls, 32);
            l_run[qi] += ls;
#pragma unroll
            for (int ch = 0; ch < 2; ++ch)
#pragma unroll
                for (int e = 0; e < 8; ++e) pa[qi][ch][e] = f2bf(p[ch * 8 + e]);
        }
        // ---- PV: 16x16x32, V fragments as contiguous b128 reads ----
#pragma unroll
        for (int ch = 0; ch < 2; ++ch) {
            const bf16x8 paA = __builtin_bit_cast(bf16x8, pa[0][ch]);
            const bf16x8 paB = __builtin_bit_cast(bf16x8, pa[1][ch]);
#pragma unroll
            for (int dt = 0; dt < 8; ++dt) {
                const bf16x8 vf = *(const bf16x8*)(Vl + (dt * 16 + c) * 72 + ch * 32 + grp * 8);
                o[0][dt] = __builtin_amdgcn_mfma_f32_16x16x32_bf16(paA, vf, o[0][dt], 0, 0, 0);
                o[1][dt] = __builtin_amdgcn_mfma_f32_16x16x32_bf16(paB, vf, o[1][dt], 0, 0, 0);
            }
        }
    }
#pragma unroll
    for (int qi = 0; qi < 2; ++qi) {
        float lo[4];
#pragma unroll
        for (int r = 0; r < 4; ++r) lo[r] = 1.0f / __shfl(l_run[qi], grp * 4 + r);
#pragma unroll
        for (int dt = 0; dt < 8; ++dt)
#pragma unroll
            for (int r = 0; r < 4; ++r) {
                const int trow = wq + qi * 16 + grp * 4 + r;
                Ob[((size_t)(b * T_SEQ) + trow) * DIM + h * HD + dt * 16 + c] = f2bf(o[qi][dt][r] * lo[r]);
            }
    }
}

extern "C" void kernel_launch(void* const* d_in, const int* in_sizes, int n_in,
                              void* d_out, int out_size, void* d_ws, size_t ws_size,
                              hipStream_t stream) {
    const float* x = (const float*)d_in[0];
    const float* wq = (const float*)d_in[1];
    const float* wk = (const float*)d_in[2];
    const float* wv = (const float*)d_in[3];
    const float* wo = (const float*)d_in[4];
    float* out = (float*)d_out;

    char* ws = (char*)d_ws;
    size_t off = 0;
    auto alloc = [&](size_t bytes) {
        char* p = ws + off;
        off = (off + bytes + 255) & ~(size_t)255;
        return p;
    };
    unsigned short* xb    = (unsigned short*)alloc((size_t)M_ROWS * DIM * 2);   // later: Qb
    unsigned short* wqkvT = (unsigned short*)alloc((size_t)QKVN * DIM * 2);     // later: Vt
    unsigned short* woT   = (unsigned short*)alloc((size_t)DIM * DIM * 2);
    unsigned short* qkv   = (unsigned short*)alloc((size_t)M_ROWS * QKVN * 2);  // later: attnO
    unsigned short* Kb    = (unsigned short*)alloc((size_t)M_ROWS * KVDIM * 2);
    unsigned short* Vb    = (unsigned short*)alloc((size_t)M_ROWS * KVDIM * 2);
    float2*         tab   = (float2*)alloc((size_t)T_SEQ * 64 * sizeof(float2));
    unsigned short* Qb    = xb;     // xb dead after QKV GEMM
    unsigned short* Vt    = wqkvT;  // wqkvT dead after QKV GEMM
    unsigned short* attnO = qkv;    // qkv dead after rope_pack

    cvt_f32_bf16<<<(M_ROWS * DIM / 4 + 255) / 256, 256, 0, stream>>>(x, xb, M_ROWS * DIM / 4);
    build_tab<<<(T_SEQ * 64 + 255) / 256, 256, 0, stream>>>(tab);

    dim3 tb(32, 8);
    transpose_cvt<<<dim3(DIM / 32, DIM / 32), tb, 0, stream>>>(wq, wqkvT, DIM, DIM);
    transpose_cvt<<<dim3(KVDIM / 32, DIM / 32), tb, 0, stream>>>(wk, wqkvT + (size_t)DIM * DIM, DIM, KVDIM);
    transpose_cvt<<<dim3(KVDIM / 32, DIM / 32), tb, 0, stream>>>(wv, wqkvT + (size_t)(DIM + KVDIM) * DIM, DIM, KVDIM);
    transpose_cvt<<<dim3(DIM / 32, DIM / 32), tb, 0, stream>>>(wo, woT, DIM, DIM);

    gemm_bt<unsigned short><<<(M_ROWS / 128) * (QKVN / 128), 256, 0, stream>>>(xb, wqkvT, qkv, M_ROWS, QKVN, DIM, M_ROWS / 128);

    rope_pack<<<M_ROWS, 256, 0, stream>>>(qkv, tab, Qb, Kb, Vb);
    transpose_v<<<dim3(T_SEQ / 32, HD / 32, B_SZ * NKV), tb, 0, stream>>>(Vb, Vt);

    attn_kernel<<<(B_SZ * NH) * (T_SEQ / QBLK), 256, 0, stream>>>(Qb, Kb, Vt, attnO);

    gemm_bt<float><<<(M_ROWS / 128) * (DIM / 128), 256, 0, stream>>>(attnO, woT, out, M_ROWS, DIM, DIM, M_ROWS / 128);
}